// Round 2
// baseline (282.583 us; speedup 1.0000x reference)
//
#include <hip/hip_runtime.h>

// Problem: B=16, C=4, H=W=512. input [B,C,H,W] f32; target [B,C+1,H,W] f32,
// last channel a {0,1} mask. Output scalar:
//   (1/B) * sum_b [ cnt_b>0 ? sum_{c,hw} mask*(in-tg)^2 / (C*cnt_b) : 0 ]
// Memory-bound: ~158 MB read. R1 showed latency-bound at 29% occupancy ->
// this round: 2048 blocks (32 waves/CU resident) + fused finalize.

#define BATCH 16
#define CHAN 4
#define HWPIX (512 * 512)           // 262144 pixels per (b,c) plane
#define BLOCKS_PER_BATCH 128
#define THREADS 256
#define TOTAL_BLOCKS (BATCH * BLOCKS_PER_BATCH)

// ws layout (floats): [0..2*BATCH) = per-batch {sum, cnt} pairs,
//                     [2*BATCH]    = block-completion counter (as uint)
#define WS_FLOATS (2 * BATCH + 1)

__global__ __launch_bounds__(THREADS) void masked_mse_fused(
    const float* __restrict__ input,
    const float* __restrict__ target,
    float* __restrict__ ws,
    float* __restrict__ out) {
    const int b   = blockIdx.x / BLOCKS_PER_BATCH;
    const int blk = blockIdx.x % BLOCKS_PER_BATCH;

    const int groups           = HWPIX / 4;                   // 65536 float4/batch
    const int groups_per_block = groups / BLOCKS_PER_BATCH;   // 512 -> 2 iters/thread

    const float* inb = input  + (size_t)b * CHAN * HWPIX;
    const float* tgb = target + (size_t)b * (CHAN + 1) * HWPIX;
    const float4* mask4 = (const float4*)(tgb + (size_t)CHAN * HWPIX);

    float s = 0.f, cnt = 0.f;

    const int g_end = (blk + 1) * groups_per_block;
#pragma unroll 2
    for (int g = blk * groups_per_block + threadIdx.x; g < g_end; g += THREADS) {
        float4 m = mask4[g];
        float mx = (m.x == 1.f) ? 1.f : 0.f;
        float my = (m.y == 1.f) ? 1.f : 0.f;
        float mz = (m.z == 1.f) ? 1.f : 0.f;
        float mw = (m.w == 1.f) ? 1.f : 0.f;
        cnt += mx + my + mz + mw;
#pragma unroll
        for (int c = 0; c < CHAN; ++c) {
            float4 a = ((const float4*)(inb + (size_t)c * HWPIX))[g];
            float4 t = ((const float4*)(tgb + (size_t)c * HWPIX))[g];
            float dx = a.x - t.x, dy = a.y - t.y, dz = a.z - t.z, dw = a.w - t.w;
            s += dx * dx * mx + dy * dy * my + dz * dz * mz + dw * dw * mw;
        }
    }

    // wave-64 shuffle reduction
#pragma unroll
    for (int off = 32; off > 0; off >>= 1) {
        s   += __shfl_down(s, off, 64);
        cnt += __shfl_down(cnt, off, 64);
    }

    __shared__ float ss[THREADS / 64];
    __shared__ float sc[THREADS / 64];
    const int lane = threadIdx.x & 63;
    const int wid  = threadIdx.x >> 6;
    if (lane == 0) { ss[wid] = s; sc[wid] = cnt; }
    __syncthreads();

    if (threadIdx.x == 0) {
        float S = 0.f, Cn = 0.f;
#pragma unroll
        for (int w = 0; w < THREADS / 64; ++w) { S += ss[w]; Cn += sc[w]; }
        atomicAdd(&ws[2 * b],     S);
        atomicAdd(&ws[2 * b + 1], Cn);

        __threadfence();  // order batch-slot atomics before the counter bump
        unsigned int* counter = (unsigned int*)&ws[2 * BATCH];
        unsigned int done = atomicAdd(counter, 1u);
        if (done == TOTAL_BLOCKS - 1) {
            // last block: finalize. Read slots via device-scope atomic
            // read-back (atomicAdd 0) to dodge cross-XCD L2 staleness.
            float acc = 0.f;
#pragma unroll
            for (int bb = 0; bb < BATCH; ++bb) {
                float sb = atomicAdd(&ws[2 * bb],     0.f);
                float cb = atomicAdd(&ws[2 * bb + 1], 0.f) * (float)CHAN;
                acc += (cb > 0.f) ? (sb / cb) : 0.f;
            }
            out[0] = acc / (float)BATCH;
        }
    }
}

extern "C" void kernel_launch(void* const* d_in, const int* in_sizes, int n_in,
                              void* d_out, int out_size, void* d_ws, size_t ws_size,
                              hipStream_t stream) {
    const float* input  = (const float*)d_in[0];
    const float* target = (const float*)d_in[1];
    float* out = (float*)d_out;
    float* ws  = (float*)d_ws;

    // zero accumulators + completion counter (d_ws is re-poisoned to 0xAA)
    hipMemsetAsync(ws, 0, WS_FLOATS * sizeof(float), stream);

    masked_mse_fused<<<dim3(TOTAL_BLOCKS), dim3(THREADS), 0, stream>>>(
        input, target, ws, out);
}

// Round 3
// 176.534 us; speedup vs baseline: 1.6007x; 1.6007x over previous
//
#include <hip/hip_runtime.h>

// Problem: B=16, C=4, H=W=512. input [B,C,H,W] f32; target [B,C+1,H,W] f32,
// last channel a {0,1} mask. Output scalar:
//   (1/B) * sum_b [ cnt_b>0 ? sum_{c,hw} mask*(in-tg)^2 / (C*cnt_b) : 0 ]
// ~158 MB read, L3-resident after harness restore. R2 lesson: NO
// __threadfence / fused finalize (L2 writeback storms serialize the chip).
// R3: R1 structure, but 512-thread blocks -> 32 waves/CU resident.

#define BATCH 16
#define CHAN 4
#define HWPIX (512 * 512)           // 262144 pixels per (b,c) plane
#define BLOCKS_PER_BATCH 64
#define THREADS 512
#define TOTAL_BLOCKS (BATCH * BLOCKS_PER_BATCH)   // 1024 = 4 blocks/CU

__global__ __launch_bounds__(THREADS) void masked_mse_partial(
    const float* __restrict__ input,
    const float* __restrict__ target,
    float* __restrict__ ws) {
    const int b   = blockIdx.x / BLOCKS_PER_BATCH;
    const int blk = blockIdx.x % BLOCKS_PER_BATCH;

    const int groups           = HWPIX / 4;                   // 65536 float4/batch
    const int groups_per_block = groups / BLOCKS_PER_BATCH;   // 1024 -> 2 iters/thread

    const float* inb = input  + (size_t)b * CHAN * HWPIX;
    const float* tgb = target + (size_t)b * (CHAN + 1) * HWPIX;
    const float4* mask4 = (const float4*)(tgb + (size_t)CHAN * HWPIX);

    float s = 0.f, cnt = 0.f;

    const int g_end = (blk + 1) * groups_per_block;
#pragma unroll 2
    for (int g = blk * groups_per_block + threadIdx.x; g < g_end; g += THREADS) {
        float4 m = mask4[g];
        float mx = (m.x == 1.f) ? 1.f : 0.f;
        float my = (m.y == 1.f) ? 1.f : 0.f;
        float mz = (m.z == 1.f) ? 1.f : 0.f;
        float mw = (m.w == 1.f) ? 1.f : 0.f;
        cnt += mx + my + mz + mw;
#pragma unroll
        for (int c = 0; c < CHAN; ++c) {
            float4 a = ((const float4*)(inb + (size_t)c * HWPIX))[g];
            float4 t = ((const float4*)(tgb + (size_t)c * HWPIX))[g];
            float dx = a.x - t.x, dy = a.y - t.y, dz = a.z - t.z, dw = a.w - t.w;
            s += dx * dx * mx + dy * dy * my + dz * dz * mz + dw * dw * mw;
        }
    }

    // wave-64 shuffle reduction
#pragma unroll
    for (int off = 32; off > 0; off >>= 1) {
        s   += __shfl_down(s, off, 64);
        cnt += __shfl_down(cnt, off, 64);
    }

    __shared__ float ss[THREADS / 64];
    __shared__ float sc[THREADS / 64];
    const int lane = threadIdx.x & 63;
    const int wid  = threadIdx.x >> 6;
    if (lane == 0) { ss[wid] = s; sc[wid] = cnt; }
    __syncthreads();

    if (threadIdx.x == 0) {
        float S = 0.f, Cn = 0.f;
#pragma unroll
        for (int w = 0; w < THREADS / 64; ++w) { S += ss[w]; Cn += sc[w]; }
        atomicAdd(&ws[2 * b],     S);
        atomicAdd(&ws[2 * b + 1], Cn);
    }
}

__global__ void masked_mse_final(const float* __restrict__ ws,
                                 float* __restrict__ out) {
    if (threadIdx.x == 0 && blockIdx.x == 0) {
        float acc = 0.f;
#pragma unroll
        for (int b = 0; b < BATCH; ++b) {
            float s  = ws[2 * b];
            float cb = ws[2 * b + 1] * (float)CHAN;   // C * #masked pixels
            acc += (cb > 0.f) ? (s / cb) : 0.f;
        }
        out[0] = acc / (float)BATCH;
    }
}

extern "C" void kernel_launch(void* const* d_in, const int* in_sizes, int n_in,
                              void* d_out, int out_size, void* d_ws, size_t ws_size,
                              hipStream_t stream) {
    const float* input  = (const float*)d_in[0];
    const float* target = (const float*)d_in[1];
    float* out = (float*)d_out;
    float* ws  = (float*)d_ws;

    // zero per-batch {sum, count} accumulators (d_ws is re-poisoned to 0xAA)
    hipMemsetAsync(ws, 0, 2 * BATCH * sizeof(float), stream);

    masked_mse_partial<<<dim3(TOTAL_BLOCKS), dim3(THREADS), 0, stream>>>(
        input, target, ws);
    masked_mse_final<<<1, 64, 0, stream>>>(ws, out);
}